// Round 1
// baseline (1174.765 us; speedup 1.0000x reference)
//
#include <hip/hip_runtime.h>

#define IN_DIM   128
#define HC       256   // HEADS*OUT_DIM
#define OUT_DIM  64
#define HEADS    4
#define NEG_SLOPE 0.2f
#define LN_EPS   1e-5f

__device__ __forceinline__ unsigned fenc(float f){
  unsigned u = __float_as_uint(f);
  return (u & 0x80000000u) ? ~u : (u | 0x80000000u);
}
__device__ __forceinline__ float fdec(unsigned u){
  return __uint_as_float((u & 0x80000000u) ? (u & 0x7FFFFFFFu) : ~u);
}
__device__ __forceinline__ float lrelu(float a){ return a > 0.f ? a : NEG_SLOPE * a; }

// Detect whether edge_index is int32 or int64 (little-endian: int64 values < 2^31
// have zero odd 32-bit words). flag[0]=1 -> int32, 0 -> int64.
__global__ void k_detect(const int* ei, long nwords, unsigned* flag){
  __shared__ unsigned s;
  if (threadIdx.x == 0) s = 0u;
  __syncthreads();
  long lim = nwords < 4096 ? nwords : 4096;
  unsigned any = 0u;
  for (long i = 1 + 2*(long)threadIdx.x; i < lim; i += 2*(long)blockDim.x)
    any |= (unsigned)ei[i];
  if (any) atomicOr(&s, 1u);
  __syncthreads();
  if (threadIdx.x == 0) flag[0] = s ? 1u : 0u;
}

__global__ void k_init(unsigned* amax, float* denom, float* out, int N){
  long i = (long)blockIdx.x*blockDim.x + threadIdx.x;
  long stride = (long)gridDim.x*blockDim.x;
  long total = (long)N*OUT_DIM;
  for (; i < total; i += stride){
    out[i] = 0.f;
    if (i < (long)N*HEADS){ amax[i] = 0u; denom[i] = 0.f; }
  }
}

// xl = x @ W  (N x 256), plus per-node attention logits a_src/a_dst (N x 4).
// Block = 256 threads (4 waves), 16 nodes per block (4 per wave).
__global__ __launch_bounds__(256) void k_gemm(
    const float* __restrict__ x, const float* __restrict__ W,
    const float* __restrict__ att_s, const float* __restrict__ att_d,
    float* __restrict__ xl, float* __restrict__ a_src, float* __restrict__ a_dst, int N)
{
  __shared__ float sx[16][IN_DIM];
  int nb = blockIdx.x * 16;
  int tid = threadIdx.x;
  const float4* xg = (const float4*)x;
  float4* sx4 = (float4*)sx;
  int base4 = nb * (IN_DIM/4);
  int lim4  = N  * (IN_DIM/4);
  for (int i = tid; i < 16*(IN_DIM/4); i += 256){
    int gi = base4 + i;
    sx4[i] = (gi < lim4) ? xg[gi] : make_float4(0.f,0.f,0.f,0.f);
  }
  __syncthreads();
  int wv = tid >> 6, ln = tid & 63;
  int n0 = wv * 4;
  float acc[4][4] = {};
  #pragma unroll 4
  for (int k = 0; k < IN_DIM; ++k){
    float w0 = W[k*HC + ln];
    float w1 = W[k*HC + 64 + ln];
    float w2 = W[k*HC + 128 + ln];
    float w3 = W[k*HC + 192 + ln];
    #pragma unroll
    for (int nn = 0; nn < 4; ++nn){
      float xv = sx[n0+nn][k];
      acc[nn][0] = fmaf(xv, w0, acc[nn][0]);
      acc[nn][1] = fmaf(xv, w1, acc[nn][1]);
      acc[nn][2] = fmaf(xv, w2, acc[nn][2]);
      acc[nn][3] = fmaf(xv, w3, acc[nn][3]);
    }
  }
  float as[4], ad[4];
  #pragma unroll
  for (int j = 0; j < 4; ++j){ as[j] = att_s[j*64+ln]; ad[j] = att_d[j*64+ln]; }
  for (int nn = 0; nn < 4; ++nn){
    int node = nb + n0 + nn;
    if (node >= N) break;
    float ss[4], dd[4];
    #pragma unroll
    for (int j = 0; j < 4; ++j){
      xl[(size_t)node*HC + j*64 + ln] = acc[nn][j];
      float vs = acc[nn][j] * as[j];
      float vd = acc[nn][j] * ad[j];
      #pragma unroll
      for (int off = 32; off; off >>= 1){
        vs += __shfl_xor(vs, off);
        vd += __shfl_xor(vd, off);
      }
      ss[j] = vs; dd[j] = vd;
    }
    if (ln == 0){
      #pragma unroll
      for (int j = 0; j < 4; ++j){ a_src[node*4+j] = ss[j]; a_dst[node*4+j] = dd[j]; }
    }
  }
}

__global__ void k_maxpass(const void* ei, const unsigned* __restrict__ flag,
    const float4* __restrict__ a_src, const float4* __restrict__ a_dst,
    unsigned* amax, long E, int N)
{
  long i = (long)blockIdx.x*blockDim.x + threadIdx.x;
  long stride = (long)gridDim.x*blockDim.x;
  long tot = E + N;
  int is32 = (int)flag[0];
  const int* e32 = (const int*)ei;
  const long long* e64 = (const long long*)ei;
  for (; i < tot; i += stride){
    int s, d;
    if (i < E){
      if (is32){ s = e32[i]; d = e32[E+i]; }
      else     { s = (int)e64[i]; d = (int)e64[E+i]; }
    } else { s = d = (int)(i - E); }
    float4 As = a_src[s], Ad = a_dst[d];
    float a0 = lrelu(As.x+Ad.x), a1 = lrelu(As.y+Ad.y);
    float a2 = lrelu(As.z+Ad.z), a3 = lrelu(As.w+Ad.w);
    atomicMax(&amax[(size_t)d*4+0], fenc(a0));
    atomicMax(&amax[(size_t)d*4+1], fenc(a1));
    atomicMax(&amax[(size_t)d*4+2], fenc(a2));
    atomicMax(&amax[(size_t)d*4+3], fenc(a3));
  }
}

__global__ void k_sumpass(const void* ei, const unsigned* __restrict__ flag,
    const float4* __restrict__ a_src, const float4* __restrict__ a_dst,
    const unsigned* __restrict__ amax, float* denom, long E, int N)
{
  long i = (long)blockIdx.x*blockDim.x + threadIdx.x;
  long stride = (long)gridDim.x*blockDim.x;
  long tot = E + N;
  int is32 = (int)flag[0];
  const int* e32 = (const int*)ei;
  const long long* e64 = (const long long*)ei;
  for (; i < tot; i += stride){
    int s, d;
    if (i < E){
      if (is32){ s = e32[i]; d = e32[E+i]; }
      else     { s = (int)e64[i]; d = (int)e64[E+i]; }
    } else { s = d = (int)(i - E); }
    float4 As = a_src[s], Ad = a_dst[d];
    float a0 = lrelu(As.x+Ad.x), a1 = lrelu(As.y+Ad.y);
    float a2 = lrelu(As.z+Ad.z), a3 = lrelu(As.w+Ad.w);
    atomicAdd(&denom[(size_t)d*4+0], __expf(a0 - fdec(amax[(size_t)d*4+0])));
    atomicAdd(&denom[(size_t)d*4+1], __expf(a1 - fdec(amax[(size_t)d*4+1])));
    atomicAdd(&denom[(size_t)d*4+2], __expf(a2 - fdec(amax[(size_t)d*4+2])));
    atomicAdd(&denom[(size_t)d*4+3], __expf(a3 - fdec(amax[(size_t)d*4+3])));
  }
}

// One wave per edge: lane c accumulates sum_h alpha_h/H * xl[src][h*64+c] into out[dst][c].
__global__ __launch_bounds__(256) void k_scatter(const void* ei, const unsigned* __restrict__ flag,
    const float4* __restrict__ a_src, const float4* __restrict__ a_dst,
    const uint4* __restrict__ amax, const float4* __restrict__ denom,
    const float* __restrict__ xl, float* out, long E, int N)
{
  int ln = threadIdx.x & 63;
  long wid = ((long)blockIdx.x*blockDim.x + threadIdx.x) >> 6;
  long nw  = ((long)gridDim.x*blockDim.x) >> 6;
  long tot = E + N;
  int is32 = (int)flag[0];
  const int* e32 = (const int*)ei;
  const long long* e64 = (const long long*)ei;
  for (long e = wid; e < tot; e += nw){
    int s, d;
    if (e < E){
      if (is32){ s = e32[e]; d = e32[E+e]; }
      else     { s = (int)e64[e]; d = (int)e64[E+e]; }
    } else { s = d = (int)(e - E); }
    float4 As = a_src[s], Ad = a_dst[d], Dn = denom[d];
    uint4  Mx = amax[d];
    float w0 = __expf(lrelu(As.x+Ad.x) - fdec(Mx.x)) / (Dn.x + 1e-16f);
    float w1 = __expf(lrelu(As.y+Ad.y) - fdec(Mx.y)) / (Dn.y + 1e-16f);
    float w2 = __expf(lrelu(As.z+Ad.z) - fdec(Mx.z)) / (Dn.z + 1e-16f);
    float w3 = __expf(lrelu(As.w+Ad.w) - fdec(Mx.w)) / (Dn.w + 1e-16f);
    const float* xr = xl + (size_t)s*HC;
    float m = 0.25f * (w0*xr[ln] + w1*xr[64+ln] + w2*xr[128+ln] + w3*xr[192+ln]);
    atomicAdd(out + (size_t)d*OUT_DIM + ln, m);
  }
}

// LayerNorm in place on out (N x 64), one wave per node.
__global__ __launch_bounds__(256) void k_ln(float* out,
    const float* __restrict__ bias, const float* __restrict__ gamma,
    const float* __restrict__ beta, int N)
{
  int wv = threadIdx.x >> 6, ln = threadIdx.x & 63;
  int node = blockIdx.x*4 + wv;
  if (node >= N) return;
  float v = out[(size_t)node*OUT_DIM + ln] + bias[ln];
  float sum = v, sq = v*v;
  #pragma unroll
  for (int off = 32; off; off >>= 1){
    sum += __shfl_xor(sum, off);
    sq  += __shfl_xor(sq, off);
  }
  float mu = sum * (1.f/OUT_DIM);
  float var = sq * (1.f/OUT_DIM) - mu*mu;
  float rs = rsqrtf(var + LN_EPS);
  out[(size_t)node*OUT_DIM + ln] = (v - mu) * rs * gamma[ln] + beta[ln];
}

extern "C" void kernel_launch(void* const* d_in, const int* in_sizes, int n_in,
                              void* d_out, int out_size, void* d_ws, size_t ws_size,
                              hipStream_t stream)
{
  const float* x     = (const float*)d_in[0];
  const void*  ei    = d_in[1];
  const float* W     = (const float*)d_in[2];
  const float* att_s = (const float*)d_in[3];
  const float* att_d = (const float*)d_in[4];
  const float* bias  = (const float*)d_in[5];
  const float* gamma = (const float*)d_in[6];
  const float* beta  = (const float*)d_in[7];
  float* out = (float*)d_out;

  int  N = in_sizes[0] / IN_DIM;
  long E = (long)in_sizes[1] / 2;

  float* wsf = (float*)d_ws;
  float*    xl    = wsf;
  float*    a_src = xl + (size_t)N*HC;
  float*    a_dst = a_src + (size_t)N*HEADS;
  unsigned* amax  = (unsigned*)(a_dst + (size_t)N*HEADS);
  float*    denom = (float*)(amax + (size_t)N*HEADS);
  unsigned* flag  = (unsigned*)(denom + (size_t)N*HEADS);

  k_detect<<<1, 256, 0, stream>>>((const int*)ei, E*2, flag);
  k_init<<<8192, 256, 0, stream>>>(amax, denom, out, N);
  k_gemm<<<(N + 15)/16, 256, 0, stream>>>(x, W, att_s, att_d, xl, a_src, a_dst, N);

  int eblk = (int)((E + N + 255) / 256);
  k_maxpass<<<eblk, 256, 0, stream>>>(ei, flag, (const float4*)a_src, (const float4*)a_dst,
                                      amax, E, N);
  k_sumpass<<<eblk, 256, 0, stream>>>(ei, flag, (const float4*)a_src, (const float4*)a_dst,
                                      amax, denom, E, N);
  k_scatter<<<8192, 256, 0, stream>>>(ei, flag, (const float4*)a_src, (const float4*)a_dst,
                                      (const uint4*)amax, (const float4*)denom, xl, out, E, N);
  k_ln<<<(N + 3)/4, 256, 0, stream>>>(out, bias, gamma, beta, N);
}

// Round 3
// 481.230 us; speedup vs baseline: 2.4412x; 2.4412x over previous
//
#include <hip/hip_runtime.h>

#define IN_DIM   128
#define HC       256   // HEADS*OUT_DIM
#define OUT_DIM  64
#define HEADS    4
#define NEG_SLOPE 0.2f
#define LN_EPS   1e-5f
#define NEG_BIG  -1e30f

__device__ __forceinline__ float lrelu(float a){ return a > 0.f ? a : NEG_SLOPE * a; }

__device__ __forceinline__ unsigned short f2bf(float f){
  unsigned u = __float_as_uint(f);
  u = u + 0x7fffu + ((u >> 16) & 1u);   // round-to-nearest-even
  return (unsigned short)(u >> 16);
}

__device__ __forceinline__ float wmax(float v){
  #pragma unroll
  for (int o = 32; o; o >>= 1) v = fmaxf(v, __shfl_xor(v, o));
  return v;
}
__device__ __forceinline__ float wsum(float v){
  #pragma unroll
  for (int o = 32; o; o >>= 1) v += __shfl_xor(v, o);
  return v;
}

// Detect int32 vs int64 edge_index layout. flag[0]=1 -> int32, 0 -> int64.
__global__ void k_detect(const int* ei, long nwords, unsigned* flag){
  __shared__ unsigned s;
  if (threadIdx.x == 0) s = 0u;
  __syncthreads();
  long lim = nwords < 4096 ? nwords : 4096;
  unsigned any = 0u;
  for (long i = 1 + 2*(long)threadIdx.x; i < lim; i += 2*(long)blockDim.x)
    any |= (unsigned)ei[i];
  if (any) atomicOr(&s, 1u);
  __syncthreads();
  if (threadIdx.x == 0) flag[0] = s ? 1u : 0u;
}

__global__ void k_zero(int* deg, int N){
  int i = blockIdx.x*blockDim.x + threadIdx.x;
  if (i < N) deg[i] = 0;
}

// xl_t = bf16(x @ W), head-interleaved: xl_t[node*256 + ch*4 + head].
// Also per-node logits a_src/a_dst (N x 4, f32).
__global__ __launch_bounds__(256) void k_gemm(
    const float* __restrict__ x, const float* __restrict__ W,
    const float* __restrict__ att_s, const float* __restrict__ att_d,
    unsigned short* __restrict__ xl_t, float* __restrict__ a_src,
    float* __restrict__ a_dst, int N)
{
  __shared__ float sx[16][IN_DIM];
  int nb = blockIdx.x * 16;
  int tid = threadIdx.x;
  const float4* xg = (const float4*)x;
  float4* sx4 = (float4*)sx;
  int base4 = nb * (IN_DIM/4);
  int lim4  = N  * (IN_DIM/4);
  for (int i = tid; i < 16*(IN_DIM/4); i += 256){
    int gi = base4 + i;
    sx4[i] = (gi < lim4) ? xg[gi] : make_float4(0.f,0.f,0.f,0.f);
  }
  __syncthreads();
  int wv = tid >> 6, ln = tid & 63;
  int n0 = wv * 4;
  float acc[4][4] = {};
  #pragma unroll 4
  for (int k = 0; k < IN_DIM; ++k){
    float w0 = W[k*HC + ln];
    float w1 = W[k*HC + 64 + ln];
    float w2 = W[k*HC + 128 + ln];
    float w3 = W[k*HC + 192 + ln];
    #pragma unroll
    for (int nn = 0; nn < 4; ++nn){
      float xv = sx[n0+nn][k];
      acc[nn][0] = fmaf(xv, w0, acc[nn][0]);
      acc[nn][1] = fmaf(xv, w1, acc[nn][1]);
      acc[nn][2] = fmaf(xv, w2, acc[nn][2]);
      acc[nn][3] = fmaf(xv, w3, acc[nn][3]);
    }
  }
  float as[4], ad[4];
  #pragma unroll
  for (int j = 0; j < 4; ++j){ as[j] = att_s[j*64+ln]; ad[j] = att_d[j*64+ln]; }
  for (int nn = 0; nn < 4; ++nn){
    int node = nb + n0 + nn;
    if (node >= N) break;
    float ss[4], dd[4];
    ushort4 pk;
    unsigned short* pb = (unsigned short*)&pk;
    #pragma unroll
    for (int j = 0; j < 4; ++j){
      pb[j] = f2bf(acc[nn][j]);
      float vs = acc[nn][j] * as[j];
      float vd = acc[nn][j] * ad[j];
      #pragma unroll
      for (int off = 32; off; off >>= 1){
        vs += __shfl_xor(vs, off);
        vd += __shfl_xor(vd, off);
      }
      ss[j] = vs; dd[j] = vd;
    }
    *(ushort4*)(xl_t + (size_t)node*HC + ln*4) = pk;
    if (ln == 0){
      #pragma unroll
      for (int j = 0; j < 4; ++j){ a_src[node*4+j] = ss[j]; a_dst[node*4+j] = dd[j]; }
    }
  }
}

__global__ void k_hist(const void* ei, const unsigned* __restrict__ flag,
                       int* deg, int E){
  int i = blockIdx.x*blockDim.x + threadIdx.x;
  if (i >= E) return;
  int d = flag[0] ? ((const int*)ei)[E+i] : (int)((const long long*)ei)[E+i];
  atomicAdd(&deg[d], 1);
}

// scan1: per-1024-chunk exclusive scan of deg into rowstart, chunk totals into partial.
__global__ __launch_bounds__(256) void k_scan1(const int* __restrict__ deg,
    int* rowstart, int* partial, int N){
  __shared__ int sh[256];
  int tid = threadIdx.x;
  int base = blockIdx.x*1024 + tid*4;
  int d[4]; int ts = 0;
  #pragma unroll
  for (int k = 0; k < 4; ++k){
    d[k] = (base+k < N) ? deg[base+k] : 0;
    ts += d[k];
  }
  sh[tid] = ts; __syncthreads();
  #pragma unroll
  for (int off = 1; off < 256; off <<= 1){
    int t = (tid >= off) ? sh[tid-off] : 0;
    __syncthreads();
    sh[tid] += t;
    __syncthreads();
  }
  int run = sh[tid] - ts;
  #pragma unroll
  for (int k = 0; k < 4; ++k){
    if (base+k < N) rowstart[base+k] = run;
    run += d[k];
  }
  if (tid == 255) partial[blockIdx.x] = sh[255];
}

// scan2: exclusive scan of up to 1024 partials (single block).
__global__ __launch_bounds__(1024) void k_scan2(int* partial, int nb){
  __shared__ int sh[1024];
  int tid = threadIdx.x;
  int v = (tid < nb) ? partial[tid] : 0;
  sh[tid] = v; __syncthreads();
  #pragma unroll
  for (int off = 1; off < 1024; off <<= 1){
    int t = (tid >= off) ? sh[tid-off] : 0;
    __syncthreads();
    sh[tid] += t;
    __syncthreads();
  }
  if (tid < nb) partial[tid] = sh[tid] - v;  // exclusive
}

// scan3: add chunk offsets, copy to cursor, set rowstart[N]=E.
__global__ void k_scan3(int* rowstart, const int* __restrict__ partial,
                        int* cursor, int N, int E){
  int i = blockIdx.x*blockDim.x + threadIdx.x;
  if (i < N){
    int v = rowstart[i] + partial[i >> 10];
    rowstart[i] = v;
    cursor[i] = v;
  }
  if (i == N) rowstart[N] = E;
}

__global__ void k_fill(const void* ei, const unsigned* __restrict__ flag,
                       int* cursor, int* csr, int E){
  int i = blockIdx.x*blockDim.x + threadIdx.x;
  if (i >= E) return;
  int s, d;
  if (flag[0]){ s = ((const int*)ei)[i]; d = ((const int*)ei)[E+i]; }
  else { s = (int)((const long long*)ei)[i]; d = (int)((const long long*)ei)[E+i]; }
  int pos = atomicAdd(&cursor[d], 1);
  csr[pos] = s;
}

// One wave per destination node: online-softmax attention over its in-edges +
// self-loop, head-average, bias, LayerNorm. Lane = output channel.
__global__ __launch_bounds__(256) void k_node(
    const int* __restrict__ rowstart, const int* __restrict__ csr,
    const float4* __restrict__ a_src4, const float4* __restrict__ a_dst4,
    const unsigned short* __restrict__ xl_t,
    const float* __restrict__ bias, const float* __restrict__ gamma,
    const float* __restrict__ beta, float* __restrict__ out, int N)
{
  int wv = threadIdx.x >> 6, ln = threadIdx.x & 63;
  int node = blockIdx.x*4 + wv;
  if (node >= N) return;

  int start = rowstart[node], end = rowstart[node+1];
  float4 ad = a_dst4[node];
  float4 asl = a_src4[node];

  // self-loop init
  float m0 = lrelu(asl.x + ad.x), m1 = lrelu(asl.y + ad.y);
  float m2 = lrelu(asl.z + ad.z), m3 = lrelu(asl.w + ad.w);
  float l0 = 1.f, l1 = 1.f, l2 = 1.f, l3 = 1.f;
  uint2 xs = *(const uint2*)(xl_t + (size_t)node*HC + ln*4);
  float acc0 = __uint_as_float(xs.x << 16);
  float acc1 = __uint_as_float(xs.x & 0xffff0000u);
  float acc2 = __uint_as_float(xs.y << 16);
  float acc3 = __uint_as_float(xs.y & 0xffff0000u);

  for (int t = start; t < end; t += 64){
    int nt = end - t; if (nt > 64) nt = 64;
    int sid = 0;
    float A0 = NEG_BIG, A1 = NEG_BIG, A2 = NEG_BIG, A3 = NEG_BIG;
    if (ln < nt){
      sid = csr[t + ln];
      float4 as4 = a_src4[sid];
      A0 = lrelu(as4.x + ad.x); A1 = lrelu(as4.y + ad.y);
      A2 = lrelu(as4.z + ad.z); A3 = lrelu(as4.w + ad.w);
    }
    float n0 = fmaxf(m0, wmax(A0)), n1 = fmaxf(m1, wmax(A1));
    float n2 = fmaxf(m2, wmax(A2)), n3 = fmaxf(m3, wmax(A3));
    float sc0 = __expf(m0-n0), sc1 = __expf(m1-n1);
    float sc2 = __expf(m2-n2), sc3 = __expf(m3-n3);
    acc0 *= sc0; acc1 *= sc1; acc2 *= sc2; acc3 *= sc3;
    l0 *= sc0; l1 *= sc1; l2 *= sc2; l3 *= sc3;
    m0 = n0; m1 = n1; m2 = n2; m3 = n3;
    float e0 = (ln < nt) ? __expf(A0 - m0) : 0.f;
    float e1 = (ln < nt) ? __expf(A1 - m1) : 0.f;
    float e2 = (ln < nt) ? __expf(A2 - m2) : 0.f;
    float e3 = (ln < nt) ? __expf(A3 - m3) : 0.f;
    l0 += wsum(e0); l1 += wsum(e1); l2 += wsum(e2); l3 += wsum(e3);

    #pragma unroll 4
    for (int j = 0; j < nt; ++j){
      int sj = __builtin_amdgcn_readlane(sid, j);
      float w0 = __uint_as_float(__builtin_amdgcn_readlane(__float_as_uint(e0), j));
      float w1 = __uint_as_float(__builtin_amdgcn_readlane(__float_as_uint(e1), j));
      float w2 = __uint_as_float(__builtin_amdgcn_readlane(__float_as_uint(e2), j));
      float w3 = __uint_as_float(__builtin_amdgcn_readlane(__float_as_uint(e3), j));
      uint2 xv = *(const uint2*)(xl_t + (size_t)sj*HC + ln*4);
      acc0 = fmaf(w0, __uint_as_float(xv.x << 16),        acc0);
      acc1 = fmaf(w1, __uint_as_float(xv.x & 0xffff0000u), acc1);
      acc2 = fmaf(w2, __uint_as_float(xv.y << 16),        acc2);
      acc3 = fmaf(w3, __uint_as_float(xv.y & 0xffff0000u), acc3);
    }
  }

  float o = 0.25f*(acc0/l0 + acc1/l1 + acc2/l2 + acc3/l3) + bias[ln];
  float s  = wsum(o);
  float sq = wsum(o*o);
  float mu = s * (1.f/OUT_DIM);
  float var = sq * (1.f/OUT_DIM) - mu*mu;
  float rs = rsqrtf(var + LN_EPS);
  out[(size_t)node*OUT_DIM + ln] = (o - mu) * rs * gamma[ln] + beta[ln];
}

extern "C" void kernel_launch(void* const* d_in, const int* in_sizes, int n_in,
                              void* d_out, int out_size, void* d_ws, size_t ws_size,
                              hipStream_t stream)
{
  const float* x     = (const float*)d_in[0];
  const void*  ei    = d_in[1];
  const float* W     = (const float*)d_in[2];
  const float* att_s = (const float*)d_in[3];
  const float* att_d = (const float*)d_in[4];
  const float* bias  = (const float*)d_in[5];
  const float* gamma = (const float*)d_in[6];
  const float* beta  = (const float*)d_in[7];
  float* out = (float*)d_out;

  int N = in_sizes[0] / IN_DIM;
  int E = in_sizes[1] / 2;

  char* ws = (char*)d_ws;
  unsigned short* xl_t = (unsigned short*)ws;          ws += (size_t)N*HC*sizeof(unsigned short);
  float* a_src = (float*)ws;                            ws += (size_t)N*HEADS*sizeof(float);
  float* a_dst = (float*)ws;                            ws += (size_t)N*HEADS*sizeof(float);
  int* deg      = (int*)ws;                             ws += (size_t)N*sizeof(int);
  int* cursor   = (int*)ws;                             ws += (size_t)N*sizeof(int);
  int* rowstart = (int*)ws;                             ws += ((size_t)N+1)*sizeof(int);
  int* partial  = (int*)ws;                             ws += 1024*sizeof(int);
  int* csr      = (int*)ws;                             ws += (size_t)E*sizeof(int);
  unsigned* flag = (unsigned*)ws;

  int nb1 = (N + 1023) / 1024;

  k_detect<<<1, 256, 0, stream>>>((const int*)ei, (long)E*2, flag);
  k_zero  <<<(N + 255)/256, 256, 0, stream>>>(deg, N);
  k_gemm  <<<(N + 15)/16, 256, 0, stream>>>(x, W, att_s, att_d, xl_t, a_src, a_dst, N);
  k_hist  <<<(E + 255)/256, 256, 0, stream>>>(ei, flag, deg, E);
  k_scan1 <<<nb1, 256, 0, stream>>>(deg, rowstart, partial, N);
  k_scan2 <<<1, 1024, 0, stream>>>(partial, nb1);
  k_scan3 <<<(N + 256)/256, 256, 0, stream>>>(rowstart, partial, cursor, N, E);
  k_fill  <<<(E + 255)/256, 256, 0, stream>>>(ei, flag, cursor, csr, E);
  k_node  <<<(N + 3)/4, 256, 0, stream>>>(rowstart, csr,
            (const float4*)a_src, (const float4*)a_dst, xl_t,
            bias, gamma, beta, out, N);
}

// Round 4
// 401.439 us; speedup vs baseline: 2.9264x; 1.1988x over previous
//
#include <hip/hip_runtime.h>

#define IN_DIM   128
#define HC       256   // HEADS*OUT_DIM
#define OUT_DIM  64
#define HEADS    4
#define NEG_SLOPE 0.2f
#define LN_EPS   1e-5f
#define NEG_BIG  -1e30f

typedef short bf16x8 __attribute__((ext_vector_type(8)));
typedef float f32x4  __attribute__((ext_vector_type(4)));

__device__ __forceinline__ float lrelu(float a){ return a > 0.f ? a : NEG_SLOPE * a; }

__device__ __forceinline__ unsigned short f2bf(float f){
  unsigned u = __float_as_uint(f);
  u = u + 0x7fffu + ((u >> 16) & 1u);   // round-to-nearest-even
  return (unsigned short)(u >> 16);
}
__device__ __forceinline__ unsigned pk2(float a, float b){
  return (unsigned)f2bf(a) | ((unsigned)f2bf(b) << 16);
}

__device__ __forceinline__ float wmax(float v){
  #pragma unroll
  for (int o = 32; o; o >>= 1) v = fmaxf(v, __shfl_xor(v, o));
  return v;
}
__device__ __forceinline__ float wsum(float v){
  #pragma unroll
  for (int o = 32; o; o >>= 1) v += __shfl_xor(v, o);
  return v;
}

// Per-wave int32/int64 layout detection: int64 node ids < 2^31 have zero odd
// 32-bit words; int32 layout would need 32 random node ids == 0 to fool this.
__device__ __forceinline__ bool detect32(const int* ei){
  int ln = threadIdx.x & 63;
  unsigned probe = (ln < 32) ? (unsigned)ei[2*ln + 1] : 0u;
  return __ballot(probe != 0) != 0ull;
}

__global__ void k_zero(int* deg, int N){
  int i = blockIdx.x*blockDim.x + threadIdx.x;
  if (i < N) deg[i] = 0;
}

// Wt[n][k] = bf16(W[k][n]) : 256 x 128 bf16, frag-friendly for MFMA B loads.
__global__ void k_wprep(const float* __restrict__ W, unsigned short* __restrict__ Wt){
  int n = blockIdx.x;          // 0..255
  int k = threadIdx.x;         // 0..127
  Wt[n*IN_DIM + k] = f2bf(W[k*HC + n]);
}

// MFMA GEMM: xl_t = bf16(x @ W) head-interleaved [node][ch*4+head],
// plus fp32 logits a_src/a_dst from the fp32 accumulators.
// Block: 16 nodes x 256 cols; 4 waves; wave w owns head w (64 cols = 4 N-tiles).
__global__ __launch_bounds__(256) void k_gemm_mfma(
    const float* __restrict__ x, const unsigned short* __restrict__ Wt,
    const float* __restrict__ att_s, const float* __restrict__ att_d,
    unsigned short* __restrict__ xl_t, float* __restrict__ a_src,
    float* __restrict__ a_dst, int N)
{
  __shared__ unsigned short sxa[16*IN_DIM];   // 4KB bf16 x-tile, XOR-swizzled
  __shared__ unsigned short sxl[16*HC];       // 8KB output staging
  int t = threadIdx.x;
  int nb = blockIdx.x * 16;

  // ---- stage A tile (16 nodes x 128 k) as bf16, swizzled ----
  {
    int row = t >> 4, seg = t & 15;
    const float* xr = x + (size_t)(nb + row)*IN_DIM + seg*8;
    float4 f0 = *(const float4*)xr;
    float4 f1 = *(const float4*)(xr + 4);
    uint4 pk;
    pk.x = pk2(f0.x, f0.y); pk.y = pk2(f0.z, f0.w);
    pk.z = pk2(f1.x, f1.y); pk.w = pk2(f1.z, f1.w);
    int byte = (row*256 + seg*16) ^ ((row & 7) << 4);
    *(uint4*)((char*)sxa + byte) = pk;
  }
  __syncthreads();

  int w = t >> 6, l = t & 63;

  // ---- A fragments: lane l holds A[row=l&15][k = ks*32 + (l>>4)*8 .. +8] ----
  bf16x8 afr[4];
  #pragma unroll
  for (int ks = 0; ks < 4; ++ks){
    int row = l & 15;
    int byte = (row*256 + ks*64 + ((l >> 4) << 4)) ^ ((row & 7) << 4);
    afr[ks] = *(const bf16x8*)((const char*)sxa + byte);
  }

  f32x4 acc[4] = {{0,0,0,0},{0,0,0,0},{0,0,0,0},{0,0,0,0}};
  #pragma unroll
  for (int nt = 0; nt < 4; ++nt){
    int col = w*64 + nt*16 + (l & 15);
    #pragma unroll
    for (int ks = 0; ks < 4; ++ks){
      // B fragment: lane l holds B[k = ks*32 + (l>>4)*8 .. +8][col = l&15 tile]
      const unsigned short* bp = Wt + (size_t)col*IN_DIM + ks*32 + ((l >> 4) << 3);
      bf16x8 bfr = *(const bf16x8*)bp;
      acc[nt] = __builtin_amdgcn_mfma_f32_16x16x32_bf16(afr[ks], bfr, acc[nt], 0, 0, 0);
    }
  }

  // ---- logits from fp32 accumulators: a[node][w] = sum_c xl*att[w][c] ----
  float attS[4], attD[4];
  #pragma unroll
  for (int nt = 0; nt < 4; ++nt){
    attS[nt] = att_s[w*64 + nt*16 + (l & 15)];
    attD[nt] = att_d[w*64 + nt*16 + (l & 15)];
  }
  #pragma unroll
  for (int r = 0; r < 4; ++r){
    float ps = 0.f, pd = 0.f;
    #pragma unroll
    for (int nt = 0; nt < 4; ++nt){
      ps = fmaf(acc[nt][r], attS[nt], ps);
      pd = fmaf(acc[nt][r], attD[nt], pd);
    }
    #pragma unroll
    for (int o = 8; o; o >>= 1){ ps += __shfl_xor(ps, o); pd += __shfl_xor(pd, o); }
    if ((l & 15) == 0){
      int node = nb + (l >> 4)*4 + r;
      a_src[node*4 + w] = ps;
      a_dst[node*4 + w] = pd;
    }
  }

  // ---- stage bf16 tile in xl_t layout, then coalesced copy-out ----
  #pragma unroll
  for (int nt = 0; nt < 4; ++nt){
    int ch = nt*16 + (l & 15);
    #pragma unroll
    for (int r = 0; r < 4; ++r){
      int row = (l >> 4)*4 + r;
      sxl[row*HC + ch*4 + w] = f2bf(acc[nt][r]);
    }
  }
  __syncthreads();
  const uint4* s4 = (const uint4*)sxl;
  uint4* g4 = (uint4*)(xl_t + (size_t)nb*HC);
  #pragma unroll
  for (int c = t; c < 512; c += 256) g4[c] = s4[c];
}

__global__ void k_hist(const int* ei, int* deg, int E){
  bool i32 = detect32(ei);
  int i = blockIdx.x*blockDim.x + threadIdx.x;
  if (i >= E) return;
  int d = i32 ? ei[E + i] : (int)((const long long*)ei)[(size_t)E + i];
  atomicAdd(&deg[d], 1);
}

// scan1: per-1024-chunk exclusive scan of deg into rowstart, chunk totals into partial.
__global__ __launch_bounds__(256) void k_scan1(const int* __restrict__ deg,
    int* rowstart, int* partial, int N){
  __shared__ int sh[256];
  int tid = threadIdx.x;
  int base = blockIdx.x*1024 + tid*4;
  int d[4]; int ts = 0;
  #pragma unroll
  for (int k = 0; k < 4; ++k){
    d[k] = (base+k < N) ? deg[base+k] : 0;
    ts += d[k];
  }
  sh[tid] = ts; __syncthreads();
  #pragma unroll
  for (int off = 1; off < 256; off <<= 1){
    int t = (tid >= off) ? sh[tid-off] : 0;
    __syncthreads();
    sh[tid] += t;
    __syncthreads();
  }
  int run = sh[tid] - ts;
  #pragma unroll
  for (int k = 0; k < 4; ++k){
    if (base+k < N) rowstart[base+k] = run;
    run += d[k];
  }
  if (tid == 255) partial[blockIdx.x] = sh[255];
}

__global__ __launch_bounds__(1024) void k_scan2(int* partial, int nb){
  __shared__ int sh[1024];
  int tid = threadIdx.x;
  int v = (tid < nb) ? partial[tid] : 0;
  sh[tid] = v; __syncthreads();
  #pragma unroll
  for (int off = 1; off < 1024; off <<= 1){
    int t = (tid >= off) ? sh[tid-off] : 0;
    __syncthreads();
    sh[tid] += t;
    __syncthreads();
  }
  if (tid < nb) partial[tid] = sh[tid] - v;  // exclusive
}

__global__ void k_scan3(int* rowstart, const int* __restrict__ partial,
                        int* cursor, int N, int E){
  int i = blockIdx.x*blockDim.x + threadIdx.x;
  if (i < N){
    int v = rowstart[i] + partial[i >> 10];
    rowstart[i] = v;
    cursor[i] = v;
  }
  if (i == N) rowstart[N] = E;
}

__global__ void k_fill(const int* ei, int* cursor, int* csr, int E){
  bool i32 = detect32(ei);
  int i = blockIdx.x*blockDim.x + threadIdx.x;
  if (i >= E) return;
  int s, d;
  if (i32){ s = ei[i]; d = ei[E + i]; }
  else {
    s = (int)((const long long*)ei)[i];
    d = (int)((const long long*)ei)[(size_t)E + i];
  }
  int pos = atomicAdd(&cursor[d], 1);
  csr[pos] = s;
}

// One wave per destination node: online-softmax attention over its in-edges +
// self-loop, head-average, bias, LayerNorm. Lane = output channel.
__global__ __launch_bounds__(256) void k_node(
    const int* __restrict__ rowstart, const int* __restrict__ csr,
    const float4* __restrict__ a_src4, const float4* __restrict__ a_dst4,
    const unsigned short* __restrict__ xl_t,
    const float* __restrict__ bias, const float* __restrict__ gamma,
    const float* __restrict__ beta, float* __restrict__ out, int N)
{
  int wv = threadIdx.x >> 6, ln = threadIdx.x & 63;
  int node = blockIdx.x*4 + wv;
  if (node >= N) return;

  int start = rowstart[node], end = rowstart[node+1];
  float4 ad = a_dst4[node];
  float4 asl = a_src4[node];

  // self-loop init
  float m0 = lrelu(asl.x + ad.x), m1 = lrelu(asl.y + ad.y);
  float m2 = lrelu(asl.z + ad.z), m3 = lrelu(asl.w + ad.w);
  float l0 = 1.f, l1 = 1.f, l2 = 1.f, l3 = 1.f;
  uint2 xs = *(const uint2*)(xl_t + (size_t)node*HC + ln*4);
  float acc0 = __uint_as_float(xs.x << 16);
  float acc1 = __uint_as_float(xs.x & 0xffff0000u);
  float acc2 = __uint_as_float(xs.y << 16);
  float acc3 = __uint_as_float(xs.y & 0xffff0000u);

  for (int t = start; t < end; t += 64){
    int nt = end - t; if (nt > 64) nt = 64;
    int sid = 0;
    float A0 = NEG_BIG, A1 = NEG_BIG, A2 = NEG_BIG, A3 = NEG_BIG;
    if (ln < nt){
      sid = csr[t + ln];
      float4 as4 = a_src4[sid];
      A0 = lrelu(as4.x + ad.x); A1 = lrelu(as4.y + ad.y);
      A2 = lrelu(as4.z + ad.z); A3 = lrelu(as4.w + ad.w);
    }
    float n0 = fmaxf(m0, wmax(A0)), n1 = fmaxf(m1, wmax(A1));
    float n2 = fmaxf(m2, wmax(A2)), n3 = fmaxf(m3, wmax(A3));
    float sc0 = __expf(m0-n0), sc1 = __expf(m1-n1);
    float sc2 = __expf(m2-n2), sc3 = __expf(m3-n3);
    acc0 *= sc0; acc1 *= sc1; acc2 *= sc2; acc3 *= sc3;
    l0 *= sc0; l1 *= sc1; l2 *= sc2; l3 *= sc3;
    m0 = n0; m1 = n1; m2 = n2; m3 = n3;
    float e0 = (ln < nt) ? __expf(A0 - m0) : 0.f;
    float e1 = (ln < nt) ? __expf(A1 - m1) : 0.f;
    float e2 = (ln < nt) ? __expf(A2 - m2) : 0.f;
    float e3 = (ln < nt) ? __expf(A3 - m3) : 0.f;
    l0 += wsum(e0); l1 += wsum(e1); l2 += wsum(e2); l3 += wsum(e3);

    #pragma unroll 8
    for (int j = 0; j < nt; ++j){
      int sj = __builtin_amdgcn_readlane(sid, j);
      float w0 = __uint_as_float(__builtin_amdgcn_readlane(__float_as_uint(e0), j));
      float w1 = __uint_as_float(__builtin_amdgcn_readlane(__float_as_uint(e1), j));
      float w2 = __uint_as_float(__builtin_amdgcn_readlane(__float_as_uint(e2), j));
      float w3 = __uint_as_float(__builtin_amdgcn_readlane(__float_as_uint(e3), j));
      uint2 xv = *(const uint2*)(xl_t + (size_t)sj*HC + ln*4);
      acc0 = fmaf(w0, __uint_as_float(xv.x << 16),        acc0);
      acc1 = fmaf(w1, __uint_as_float(xv.x & 0xffff0000u), acc1);
      acc2 = fmaf(w2, __uint_as_float(xv.y << 16),        acc2);
      acc3 = fmaf(w3, __uint_as_float(xv.y & 0xffff0000u), acc3);
    }
  }

  float o = 0.25f*(acc0/l0 + acc1/l1 + acc2/l2 + acc3/l3) + bias[ln];
  float s  = wsum(o);
  float sq = wsum(o*o);
  float mu = s * (1.f/OUT_DIM);
  float var = sq * (1.f/OUT_DIM) - mu*mu;
  float rs = rsqrtf(var + LN_EPS);
  out[(size_t)node*OUT_DIM + ln] = (o - mu) * rs * gamma[ln] + beta[ln];
}

extern "C" void kernel_launch(void* const* d_in, const int* in_sizes, int n_in,
                              void* d_out, int out_size, void* d_ws, size_t ws_size,
                              hipStream_t stream)
{
  const float* x     = (const float*)d_in[0];
  const int*   ei    = (const int*)d_in[1];
  const float* W     = (const float*)d_in[2];
  const float* att_s = (const float*)d_in[3];
  const float* att_d = (const float*)d_in[4];
  const float* bias  = (const float*)d_in[5];
  const float* gamma = (const float*)d_in[6];
  const float* beta  = (const float*)d_in[7];
  float* out = (float*)d_out;

  int N = in_sizes[0] / IN_DIM;
  int E = in_sizes[1] / 2;

  char* ws = (char*)d_ws;
  unsigned short* xl_t = (unsigned short*)ws;   ws += (size_t)N*HC*sizeof(unsigned short);
  float* a_src = (float*)ws;                    ws += (size_t)N*HEADS*sizeof(float);
  float* a_dst = (float*)ws;                    ws += (size_t)N*HEADS*sizeof(float);
  int* deg      = (int*)ws;                     ws += (size_t)N*sizeof(int);
  int* cursor   = (int*)ws;                     ws += (size_t)N*sizeof(int);
  int* rowstart = (int*)ws;                     ws += ((size_t)N+1)*sizeof(int);
  int* partial  = (int*)ws;                     ws += 1024*sizeof(int);
  int* csr      = (int*)ws;                     ws += (size_t)E*sizeof(int);
  unsigned short* Wt = (unsigned short*)ws;     ws += (size_t)HC*IN_DIM*sizeof(unsigned short);

  int nb1 = (N + 1023) / 1024;

  k_zero  <<<(N + 255)/256, 256, 0, stream>>>(deg, N);
  k_wprep <<<HC, IN_DIM, 0, stream>>>(W, Wt);
  k_gemm_mfma<<<(N + 15)/16, 256, 0, stream>>>(x, Wt, att_s, att_d, xl_t, a_src, a_dst, N);
  k_hist  <<<(E + 255)/256, 256, 0, stream>>>(ei, deg, E);
  k_scan1 <<<nb1, 256, 0, stream>>>(deg, rowstart, partial, N);
  k_scan2 <<<1, 1024, 0, stream>>>(partial, nb1);
  k_scan3 <<<(N + 256)/256, 256, 0, stream>>>(rowstart, partial, cursor, N, E);
  k_fill  <<<(E + 255)/256, 256, 0, stream>>>(ei, cursor, csr, E);
  k_node  <<<(N + 3)/4, 256, 0, stream>>>(rowstart, csr,
            (const float4*)a_src, (const float4*)a_dst, xl_t,
            bias, gamma, beta, out, N);
}